// Round 5
// baseline (234.293 us; speedup 1.0000x reference)
//
#include <hip/hip_runtime.h>
#include <stdint.h>

// ---------------------------------------------------------------------------
// Causal self-attention, MI355X bf16-MFMA, round 13.
//   1. cast_all: x -> bf16, wq|wk|wv|wo -> bf16 (wq pre-scaled by 1/8*log2e)
//   2. gemm_qkv: REVERTED to round-10 128^2 BK=64 version (measured 59.7 us,
//      863 TF = this structure's documented ceiling). Two 256^2 8-phase
//      attempts (r11: 87us, r12: 83.5us) both landed everything-idle; parked.
//   3. attn: 32x32x16 MFMA, swapped QK^T, in-register P (round-10 verified)
//      + NEW: 3-deep LDS ring with counted vmcnt(4) (one tile's 4 loads stay
//      in flight across the barrier; vmcnt(0) only on the last tile).
//   4. gemm_out: out = O @ wo.T (fp32), 128^2 structure
// ---------------------------------------------------------------------------

typedef __attribute__((ext_vector_type(8))) short bf16x8;
typedef __attribute__((ext_vector_type(4))) float f32x4;
typedef __attribute__((ext_vector_type(16))) float f32x16;
typedef unsigned short us;
typedef unsigned int u32;

#define LOG2E 1.4426950408889634f

#define GL2LDS16(g, l)                                                          \
  __builtin_amdgcn_global_load_lds(                                             \
      (const __attribute__((address_space(1))) unsigned int*)(g),               \
      (__attribute__((address_space(3))) unsigned int*)(l), 16, 0, 0)

__device__ inline us f2bf(float f) {
  union { float f; unsigned int u; } v; v.f = f;
  unsigned int u = v.u;
  u += 0x7FFFu + ((u >> 16) & 1u);
  return (us)(u >> 16);
}

// ---------------------------- fused casts ----------------------------------
__global__ void cast_all(const float* __restrict__ x,
                         const float* __restrict__ w0, const float* __restrict__ w1,
                         const float* __restrict__ w2, const float* __restrict__ w3,
                         us* __restrict__ xb, us* __restrict__ wbuf) {
  int i = (blockIdx.x * blockDim.x + threadIdx.x) * 8;
  const float* src;
  us* dst;
  float sc = 1.0f;
  if (i < (8 << 20)) {
    src = x + i; dst = xb + i;
  } else {
    int j = i - (8 << 20);
    int seg = j >> 20;
    int off = j & ((1 << 20) - 1);
    const float* w = (seg == 0) ? w0 : (seg == 1) ? w1 : (seg == 2) ? w2 : w3;
    if (seg == 0) sc = 0.125f * LOG2E;
    src = w + off; dst = wbuf + j;
  }
  float4 a = *reinterpret_cast<const float4*>(src);
  float4 b = *reinterpret_cast<const float4*>(src + 4);
  union { us u[8]; uint4 v; } o;
  o.u[0] = f2bf(a.x * sc); o.u[1] = f2bf(a.y * sc);
  o.u[2] = f2bf(a.z * sc); o.u[3] = f2bf(a.w * sc);
  o.u[4] = f2bf(b.x * sc); o.u[5] = f2bf(b.y * sc);
  o.u[6] = f2bf(b.z * sc); o.u[7] = f2bf(b.w * sc);
  *reinterpret_cast<uint4*>(dst) = o.v;
}

// -------------------- QKV GEMM (B^T), BK=64, fused V-transpose -------------
// Round-10 version (measured 59.7 us): 128^2 tile, 256 thr, 2 blocks/CU.
__global__ __launch_bounds__(256, 2) void gemm_qkv(
    const us* __restrict__ A, const us* __restrict__ Bw,
    us* __restrict__ QKV, us* __restrict__ Vt) {
  const int K = 1024, N = 3072;
  __shared__ __align__(16) us Al[128 * 64];
  __shared__ __align__(16) us Bl[128 * 64];
  const int tid = threadIdx.x;
  const int lane = tid & 63;
  const int w = tid >> 6;
  const int quad = lane >> 4;
  const int l16 = lane & 15;
  const int m0 = blockIdx.y * 128;
  const int n0 = blockIdx.x * 128;
  const int wm = w >> 1, wn = w & 1;
  const int srow_base = w * 8 + (lane >> 3);
  const int sunit = lane & 7;
  f32x4 acc[4][4] = {};

  for (int k0 = 0; k0 < K; k0 += 64) {
    __syncthreads();
#pragma unroll
    for (int it = 0; it < 4; ++it) {
      int row = it * 32 + srow_base;
      int gu = sunit ^ (row & 7);
      int base = __builtin_amdgcn_readfirstlane((it * 256 + w * 64) * 8);
      GL2LDS16(A + (size_t)(m0 + row) * K + k0 + gu * 8, &Al[base]);
      GL2LDS16(Bw + (size_t)(n0 + row) * K + k0 + gu * 8, &Bl[base]);
    }
    __syncthreads();
#pragma unroll
    for (int kk = 0; kk < 2; ++kk) {
      bf16x8 af[4], bfr[4];
#pragma unroll
      for (int mi = 0; mi < 4; ++mi) {
        int row = wm * 64 + mi * 16 + l16;
        af[mi] = *reinterpret_cast<const bf16x8*>(
            &Al[row * 64 + (((kk * 4 + quad) ^ (row & 7)) * 8)]);
      }
#pragma unroll
      for (int ni = 0; ni < 4; ++ni) {
        int row = wn * 64 + ni * 16 + l16;
        bfr[ni] = *reinterpret_cast<const bf16x8*>(
            &Bl[row * 64 + (((kk * 4 + quad) ^ (row & 7)) * 8)]);
      }
#pragma unroll
      for (int mi = 0; mi < 4; ++mi)
#pragma unroll
        for (int ni = 0; ni < 4; ++ni)
          acc[mi][ni] = __builtin_amdgcn_mfma_f32_16x16x32_bf16(af[mi], bfr[ni], acc[mi][ni], 0, 0, 0);
    }
  }

  if (n0 < 2048) {
#pragma unroll
    for (int mi = 0; mi < 4; ++mi)
#pragma unroll
      for (int ni = 0; ni < 4; ++ni)
#pragma unroll
        for (int r = 0; r < 4; ++r) {
          int row = m0 + wm * 64 + mi * 16 + quad * 4 + r;
          int col = n0 + wn * 64 + ni * 16 + l16;
          QKV[(size_t)row * N + col] = f2bf(acc[mi][ni][r]);
        }
  } else {
    // V columns: write V^T in NATURAL k-order: Vt[(b*16+h)*64 + d][t]
    const int bI = m0 >> 11;
    const int tbase = m0 & 2047;
#pragma unroll
    for (int mi = 0; mi < 4; ++mi)
#pragma unroll
      for (int ni = 0; ni < 4; ++ni)
#pragma unroll
        for (int r = 0; r < 4; ++r) {
          int krow = tbase + wm * 64 + mi * 16 + quad * 4 + r;
          int col = n0 + wn * 64 + ni * 16 + l16;
          int hh = (col - 2048) >> 6;
          int d = col & 63;
          Vt[((size_t)((bI * 16 + hh) * 64 + d)) * 2048 + krow] = f2bf(acc[mi][ni][r]);
        }
  }
}

// ------------------------- out-proj GEMM (B^T), BK=64 ----------------------
__global__ __launch_bounds__(256, 2) void gemm_out(
    const us* __restrict__ A, const us* __restrict__ Bw,
    float* __restrict__ Cv, int M, int N, int K) {
  __shared__ __align__(16) us Al[128 * 64];
  __shared__ __align__(16) us Bl[128 * 64];
  const int tid = threadIdx.x;
  const int lane = tid & 63;
  const int w = tid >> 6;
  const int quad = lane >> 4;
  const int l16 = lane & 15;
  const int m0 = blockIdx.y * 128;
  const int n0 = blockIdx.x * 128;
  const int wm = w >> 1, wn = w & 1;
  const int srow_base = w * 8 + (lane >> 3);
  const int sunit = lane & 7;
  f32x4 acc[4][4] = {};

  for (int k0 = 0; k0 < K; k0 += 64) {
    __syncthreads();
#pragma unroll
    for (int it = 0; it < 4; ++it) {
      int row = it * 32 + srow_base;
      int gu = sunit ^ (row & 7);
      int base = __builtin_amdgcn_readfirstlane((it * 256 + w * 64) * 8);
      GL2LDS16(A + (size_t)(m0 + row) * K + k0 + gu * 8, &Al[base]);
      GL2LDS16(Bw + (size_t)(n0 + row) * K + k0 + gu * 8, &Bl[base]);
    }
    __syncthreads();
#pragma unroll
    for (int kk = 0; kk < 2; ++kk) {
      bf16x8 af[4], bfr[4];
#pragma unroll
      for (int mi = 0; mi < 4; ++mi) {
        int row = wm * 64 + mi * 16 + l16;
        af[mi] = *reinterpret_cast<const bf16x8*>(
            &Al[row * 64 + (((kk * 4 + quad) ^ (row & 7)) * 8)]);
      }
#pragma unroll
      for (int ni = 0; ni < 4; ++ni) {
        int row = wn * 64 + ni * 16 + l16;
        bfr[ni] = *reinterpret_cast<const bf16x8*>(
            &Bl[row * 64 + (((kk * 4 + quad) ^ (row & 7)) * 8)]);
      }
#pragma unroll
      for (int mi = 0; mi < 4; ++mi)
#pragma unroll
        for (int ni = 0; ni < 4; ++ni)
          acc[mi][ni] = __builtin_amdgcn_mfma_f32_16x16x32_bf16(af[mi], bfr[ni], acc[mi][ni], 0, 0, 0);
    }
  }

#pragma unroll
  for (int mi = 0; mi < 4; ++mi)
#pragma unroll
    for (int ni = 0; ni < 4; ++ni)
#pragma unroll
      for (int r = 0; r < 4; ++r) {
        int row = m0 + wm * 64 + mi * 16 + quad * 4 + r;
        int col = n0 + wn * 64 + ni * 16 + l16;
        Cv[(size_t)row * N + col] = acc[mi][ni][r];
      }
}

// ---------------------------- flash attention ------------------------------
// 32x32x16 MFMA. Block = 4 waves x 32 q-rows = 128 q. 1024 blocks.
// Swapped QK^T: s = mfma(K, Q) -> lane holds P[k(r,hi)][q=lane&31].
// Per-subtile pipeline keeps s/p/pk live for one 32k subtile only.
// NEW (r13): 3-deep LDS ring + counted vmcnt(4): stage(kt+1)'s 4 loads stay
// in flight across the barrier; vmcnt(0) only when kt is the last tile.
// Invariants: read-visibility -- each wave drains its own stage(kt) before
// the barrier, so after the barrier buf[kt%3] is fully staged; overwrite --
// stage(kt+2) (issued after iter-kt barrier) writes buf[(kt+2)%3] =
// buf[(kt-1)%3], last read in iter kt-1, sealed by this barrier.
__global__ __launch_bounds__(256, 3) void attn(
    const us* __restrict__ QKV, const us* __restrict__ Vt,
    us* __restrict__ O) {
  __shared__ __align__(16) us Kb[3][64 * 64];
  __shared__ __align__(16) us Vb[3][64 * 64];
  __shared__ float Ls[4][32];
  const int bid = blockIdx.x;
  // balanced qt order: round-robin CU groups each get sum(2qt+2) == const
  const int j16 = bid >> 6;
  const int grp = j16 >> 2, pos = j16 & 3;
  const int qt = (grp == 0) ? 15 - pos : (grp == 1) ? pos
               : (grp == 2) ? 11 - pos : 4 + pos;
  const int bh = bid & 63;
  const int b = bh >> 4, h = bh & 15;
  const int q0 = qt * 128;
  const int tid = threadIdx.x, lane = tid & 63, w = tid >> 6;   // w in [0,4)
  const int l31 = lane & 31, hi = lane >> 5;
  const size_t rowbase = (size_t)b * 2048;
  const int qcol = h * 64;
  const int kcol = 1024 + h * 64;
  const int qw = q0 + w * 32;              // this wave's 32-row strip
  const int nT = 2 * qt + 2;

  // bank swizzle mask for reads (row = t*32 + l31; +32 doesn't change it)
  const int mr = (l31 & 7) ^ ((l31 >> 3) & 3);

  // Q B-fragments: lane(col=q=l31) holds Q[q][ds*16 + hi*8 + j]
  bf16x8 qf[4];
#pragma unroll
  for (int ds = 0; ds < 4; ++ds)
    qf[ds] = *reinterpret_cast<const bf16x8*>(
        &QKV[(rowbase + qw + l31) * 3072 + qcol + ds * 16 + hi * 8]);

  f32x16 oacc[2] = {};
  float psum = 0.f;

  const int rr8 = w * 8 + (lane >> 3);     // staged row within 32-row chunk
  const int ms = (rr8 & 7) ^ ((rr8 >> 3) & 3);
  const int uu = lane & 7;
  const int gu = uu ^ ms;                  // pre-swizzled source unit

  auto stage = [&](int kt, int buf) {
#pragma unroll
    for (int c = 0; c < 2; ++c) {
      int row = c * 32 + rr8;
      int base = __builtin_amdgcn_readfirstlane((c * 32 + w * 8) * 64);
      GL2LDS16(QKV + (rowbase + kt * 64 + row) * 3072 + kcol + gu * 8,
               &Kb[buf][base]);
      GL2LDS16(Vt + ((size_t)(bh * 64 + row)) * 2048 + kt * 64 + gu * 8,
               &Vb[buf][base]);
    }
  };

  stage(0, 0);
  stage(1, 1);

  int cur = 0;                              // kt % 3
  for (int kt = 0; kt < nT; ++kt) {
    if (kt < nT - 1) {
      asm volatile("s_waitcnt vmcnt(4)" ::: "memory");  // own stage(kt) done
    } else {
      asm volatile("s_waitcnt vmcnt(0)" ::: "memory");  // last tile: drain
    }
    asm volatile("s_barrier" ::: "memory");             // tile kt staged by all
    if (kt + 2 < nT) {
      int nxt = cur + 2; if (nxt >= 3) nxt -= 3;
      stage(kt + 2, nxt);
    }
    const us* Kl = &Kb[cur][0];
    const us* Vl = &Vb[cur][0];
    ++cur; if (cur == 3) cur = 0;

    const int kdiff = qw + 31 - kt * 64;
    if (kdiff < 0) continue;                          // strip above diagonal
    const int tmax = (kdiff >= 32) ? 2 : 1;
    const bool do_mask = (kt * 64 + 63) > qw;

#pragma unroll
    for (int t = 0; t < 2; ++t) {
      if (t < tmax) {
        // swapped QK^T subtile: s = K_sub(t) * Q^T -> D[k][q], col=q=l31
        f32x16 s = {};
#pragma unroll
        for (int ds = 0; ds < 4; ++ds) {
          int row = t * 32 + l31;
          bf16x8 kf = *reinterpret_cast<const bf16x8*>(
              &Kl[row * 64 + (((ds * 2 + hi) ^ mr) * 8)]);
          s = __builtin_amdgcn_mfma_f32_32x32x16_bf16(kf, qf[ds], s, 0, 0, 0);
        }

        // exp2 + mask + per-lane row-sum
        float p[16];
        if (do_mask) {
#pragma unroll
          for (int r = 0; r < 16; ++r) {
            float e = __builtin_amdgcn_exp2f(s[r]);
            int kg = kt * 64 + t * 32 + (r & 3) + ((r >> 2) << 3) + hi * 4;
            p[r] = (kg <= qw + l31) ? e : 0.f;
            psum += p[r];
          }
        } else {
#pragma unroll
          for (int r = 0; r < 16; ++r) {
            p[r] = __builtin_amdgcn_exp2f(s[r]);
            psum += p[r];
          }
        }

        // pk[bb][w2] = bf16pair(p[4bb+2w2], p[4bb+2w2+1]); block (2bb+hi) of k
        u32 pk[4][2];
#pragma unroll
        for (int bb = 0; bb < 4; ++bb)
#pragma unroll
          for (int w2 = 0; w2 < 2; ++w2)
            asm("v_cvt_pk_bf16_f32 %0, %1, %2"
                : "=v"(pk[bb][w2])
                : "v"(p[4 * bb + 2 * w2]), "v"(p[4 * bb + 2 * w2 + 1]));

        // slice s2: dest half hi needs pk[2*s2+hi] from both halves
#pragma unroll
        for (int s2 = 0; s2 < 2; ++s2) {
          u32 pa[4];
#pragma unroll
          for (int w2 = 0; w2 < 2; ++w2) {
            u32 a = pk[2 * s2][w2];
            u32 c = pk[2 * s2 + 1][w2];
            asm volatile("v_permlane32_swap_b32 %0, %1" : "+v"(a), "+v"(c));
            pa[w2] = a;            // j 0..3  (k = 16*s2 + 8*hi + 0..3)
            pa[2 + w2] = c;        // j 4..7
          }
          union { u32 u[4]; bf16x8 v; } pu;
          pu.u[0] = pa[0]; pu.u[1] = pa[1]; pu.u[2] = pa[2]; pu.u[3] = pa[3];
          bf16x8 paf = pu.v;
          int ks = t * 2 + s2;     // 16k slice within the 64k tile
#pragma unroll
          for (int dt = 0; dt < 2; ++dt) {
            int row = dt * 32 + l31;
            bf16x8 vf = *reinterpret_cast<const bf16x8*>(
                &Vl[row * 64 + (((ks * 2 + hi) ^ mr) * 8)]);
            oacc[dt] = __builtin_amdgcn_mfma_f32_32x32x16_bf16(paf, vf, oacc[dt], 0, 0, 0);
          }
        }
      }
    }
  }

  // combine psum halves (disjoint k-sets) and broadcast 1/sum via LDS
  {
    float a = psum, c = psum;
    asm volatile("v_permlane32_swap_b32 %0, %1" : "+v"(a), "+v"(c));
    float invl = 1.0f / (a + c);
    if (!hi) Ls[w][l31] = invl;
    asm volatile("s_waitcnt lgkmcnt(0)" ::: "memory");  // wave-local
  }
  float inv[16];
#pragma unroll
  for (int r = 0; r < 16; ++r)
    inv[r] = Ls[w][(r & 3) + ((r >> 2) << 3) + hi * 4];
#pragma unroll
  for (int dt = 0; dt < 2; ++dt)
#pragma unroll
    for (int r = 0; r < 16; ++r) {
      int qg = qw + (r & 3) + ((r >> 2) << 3) + hi * 4;
      O[(rowbase + qg) * 1024 + qcol + dt * 32 + l31] = f2bf(oacc[dt][r] * inv[r]);
    }
}

// ------------------------------- launcher ----------------------------------
extern "C" void kernel_launch(void* const* d_in, const int* in_sizes, int n_in,
                              void* d_out, int out_size, void* d_ws, size_t ws_size,
                              hipStream_t stream) {
  const float* x = (const float*)d_in[0];
  const float* wq = (const float*)d_in[1];
  const float* wk = (const float*)d_in[2];
  const float* wv = (const float*)d_in[3];
  const float* wo = (const float*)d_in[4];

  const int BT = 8192, E = 1024;
  const size_t NX = (size_t)BT * E;
  const size_t NW = (size_t)E * E;

  us* xb = (us*)d_ws;                 // [8192][1024]; later reused as O
  us* wbuf = xb + NX;                 // wq|wk|wv|wo bf16
  us* QKV = wbuf + 4 * NW;            // [8192][3072] (V cols unused)
  us* VtB = QKV + (size_t)BT * 3 * E; // [64 bh][64 d][2048], natural k-order
  us* Ob = xb;

  cast_all<<<(int)((NX + 4 * NW) / 8 / 256), 256, 0, stream>>>(x, wq, wk, wv, wo, xb, wbuf);

  gemm_qkv<<<dim3(24, 64), 256, 0, stream>>>(xb, wbuf, QKV, VtB);
  attn<<<1024, 256, 0, stream>>>(QKV, VtB, Ob);
  gemm_out<<<dim3(8, 64), 256, 0, stream>>>(Ob, wbuf + 3 * NW, (float*)d_out, BT, E, E);
}

// Round 6
// 222.481 us; speedup vs baseline: 1.0531x; 1.0531x over previous
//
#include <hip/hip_runtime.h>
#include <stdint.h>

// ---------------------------------------------------------------------------
// Causal self-attention, MI355X bf16-MFMA, round 14.
//   1. cast_all: x -> bf16, wq|wk|wv|wo -> bf16 (wq pre-scaled by 1/8*log2e)
//   2. gemm_qkv: round-10 128^2 BK=64 structure + TWO changes:
//      (a) __launch_bounds__(256,3): 3 blocks/CU (m97-structure's known-good
//          occupancy), (b) XCD-aware bijective swizzle (1536 = 8 x 192;
//          chunk = 8 m-panels x 24 n-panels -> ~8 MB/XCD working set).
//   3. attn: REVERTED to round-10 exact (2-deep ring, vmcnt(0)) -- the r13
//      3-ring was unresolvable vs noise; keep the verified-best version.
//   4. gemm_out: out = O @ wo.T (fp32), unchanged.
// ---------------------------------------------------------------------------

typedef __attribute__((ext_vector_type(8))) short bf16x8;
typedef __attribute__((ext_vector_type(4))) float f32x4;
typedef __attribute__((ext_vector_type(16))) float f32x16;
typedef unsigned short us;
typedef unsigned int u32;

#define LOG2E 1.4426950408889634f

#define GL2LDS16(g, l)                                                          \
  __builtin_amdgcn_global_load_lds(                                             \
      (const __attribute__((address_space(1))) unsigned int*)(g),               \
      (__attribute__((address_space(3))) unsigned int*)(l), 16, 0, 0)

__device__ inline us f2bf(float f) {
  union { float f; unsigned int u; } v; v.f = f;
  unsigned int u = v.u;
  u += 0x7FFFu + ((u >> 16) & 1u);
  return (us)(u >> 16);
}

// ---------------------------- fused casts ----------------------------------
__global__ void cast_all(const float* __restrict__ x,
                         const float* __restrict__ w0, const float* __restrict__ w1,
                         const float* __restrict__ w2, const float* __restrict__ w3,
                         us* __restrict__ xb, us* __restrict__ wbuf) {
  int i = (blockIdx.x * blockDim.x + threadIdx.x) * 8;
  const float* src;
  us* dst;
  float sc = 1.0f;
  if (i < (8 << 20)) {
    src = x + i; dst = xb + i;
  } else {
    int j = i - (8 << 20);
    int seg = j >> 20;
    int off = j & ((1 << 20) - 1);
    const float* w = (seg == 0) ? w0 : (seg == 1) ? w1 : (seg == 2) ? w2 : w3;
    if (seg == 0) sc = 0.125f * LOG2E;
    src = w + off; dst = wbuf + j;
  }
  float4 a = *reinterpret_cast<const float4*>(src);
  float4 b = *reinterpret_cast<const float4*>(src + 4);
  union { us u[8]; uint4 v; } o;
  o.u[0] = f2bf(a.x * sc); o.u[1] = f2bf(a.y * sc);
  o.u[2] = f2bf(a.z * sc); o.u[3] = f2bf(a.w * sc);
  o.u[4] = f2bf(b.x * sc); o.u[5] = f2bf(b.y * sc);
  o.u[6] = f2bf(b.z * sc); o.u[7] = f2bf(b.w * sc);
  *reinterpret_cast<uint4*>(dst) = o.v;
}

// -------------------- QKV GEMM (B^T), BK=64, fused V-transpose -------------
// r10 structure; r14: 3 blocks/CU + XCD-bijective swizzle (8 chunks of 192,
// chunk = m-rows [c*8,c*8+8) x all 24 n-cols).
__global__ __launch_bounds__(256, 3) void gemm_qkv(
    const us* __restrict__ A, const us* __restrict__ Bw,
    us* __restrict__ QKV, us* __restrict__ Vt) {
  const int K = 1024, N = 3072;
  __shared__ __align__(16) us Al[128 * 64];
  __shared__ __align__(16) us Bl[128 * 64];
  const int tid = threadIdx.x;
  const int lane = tid & 63;
  const int w = tid >> 6;
  const int quad = lane >> 4;
  const int l16 = lane & 15;
  const int bid = blockIdx.x;                 // 0..1535
  const int xcd = bid & 7;
  const int idx = bid >> 3;                   // 0..191
  const int mt = xcd * 8 + idx / 24;          // 0..63
  const int nt = idx % 24;                    // 0..23
  const int m0 = mt * 128;
  const int n0 = nt * 128;
  const int wm = w >> 1, wn = w & 1;
  const int srow_base = w * 8 + (lane >> 3);
  const int sunit = lane & 7;
  f32x4 acc[4][4] = {};

  for (int k0 = 0; k0 < K; k0 += 64) {
    __syncthreads();
#pragma unroll
    for (int it = 0; it < 4; ++it) {
      int row = it * 32 + srow_base;
      int gu = sunit ^ (row & 7);
      int base = __builtin_amdgcn_readfirstlane((it * 256 + w * 64) * 8);
      GL2LDS16(A + (size_t)(m0 + row) * K + k0 + gu * 8, &Al[base]);
      GL2LDS16(Bw + (size_t)(n0 + row) * K + k0 + gu * 8, &Bl[base]);
    }
    __syncthreads();
#pragma unroll
    for (int kk = 0; kk < 2; ++kk) {
      bf16x8 af[4], bfr[4];
#pragma unroll
      for (int mi = 0; mi < 4; ++mi) {
        int row = wm * 64 + mi * 16 + l16;
        af[mi] = *reinterpret_cast<const bf16x8*>(
            &Al[row * 64 + (((kk * 4 + quad) ^ (row & 7)) * 8)]);
      }
#pragma unroll
      for (int ni = 0; ni < 4; ++ni) {
        int row = wn * 64 + ni * 16 + l16;
        bfr[ni] = *reinterpret_cast<const bf16x8*>(
            &Bl[row * 64 + (((kk * 4 + quad) ^ (row & 7)) * 8)]);
      }
#pragma unroll
      for (int mi = 0; mi < 4; ++mi)
#pragma unroll
        for (int ni = 0; ni < 4; ++ni)
          acc[mi][ni] = __builtin_amdgcn_mfma_f32_16x16x32_bf16(af[mi], bfr[ni], acc[mi][ni], 0, 0, 0);
    }
  }

  if (n0 < 2048) {
#pragma unroll
    for (int mi = 0; mi < 4; ++mi)
#pragma unroll
      for (int ni = 0; ni < 4; ++ni)
#pragma unroll
        for (int r = 0; r < 4; ++r) {
          int row = m0 + wm * 64 + mi * 16 + quad * 4 + r;
          int col = n0 + wn * 64 + ni * 16 + l16;
          QKV[(size_t)row * N + col] = f2bf(acc[mi][ni][r]);
        }
  } else {
    // V columns: write V^T in NATURAL k-order: Vt[(b*16+h)*64 + d][t]
    const int bI = m0 >> 11;
    const int tbase = m0 & 2047;
#pragma unroll
    for (int mi = 0; mi < 4; ++mi)
#pragma unroll
      for (int ni = 0; ni < 4; ++ni)
#pragma unroll
        for (int r = 0; r < 4; ++r) {
          int krow = tbase + wm * 64 + mi * 16 + quad * 4 + r;
          int col = n0 + wn * 64 + ni * 16 + l16;
          int hh = (col - 2048) >> 6;
          int d = col & 63;
          Vt[((size_t)((bI * 16 + hh) * 64 + d)) * 2048 + krow] = f2bf(acc[mi][ni][r]);
        }
  }
}

// ------------------------- out-proj GEMM (B^T), BK=64 ----------------------
__global__ __launch_bounds__(256, 2) void gemm_out(
    const us* __restrict__ A, const us* __restrict__ Bw,
    float* __restrict__ Cv, int M, int N, int K) {
  __shared__ __align__(16) us Al[128 * 64];
  __shared__ __align__(16) us Bl[128 * 64];
  const int tid = threadIdx.x;
  const int lane = tid & 63;
  const int w = tid >> 6;
  const int quad = lane >> 4;
  const int l16 = lane & 15;
  const int m0 = blockIdx.y * 128;
  const int n0 = blockIdx.x * 128;
  const int wm = w >> 1, wn = w & 1;
  const int srow_base = w * 8 + (lane >> 3);
  const int sunit = lane & 7;
  f32x4 acc[4][4] = {};

  for (int k0 = 0; k0 < K; k0 += 64) {
    __syncthreads();
#pragma unroll
    for (int it = 0; it < 4; ++it) {
      int row = it * 32 + srow_base;
      int gu = sunit ^ (row & 7);
      int base = __builtin_amdgcn_readfirstlane((it * 256 + w * 64) * 8);
      GL2LDS16(A + (size_t)(m0 + row) * K + k0 + gu * 8, &Al[base]);
      GL2LDS16(Bw + (size_t)(n0 + row) * K + k0 + gu * 8, &Bl[base]);
    }
    __syncthreads();
#pragma unroll
    for (int kk = 0; kk < 2; ++kk) {
      bf16x8 af[4], bfr[4];
#pragma unroll
      for (int mi = 0; mi < 4; ++mi) {
        int row = wm * 64 + mi * 16 + l16;
        af[mi] = *reinterpret_cast<const bf16x8*>(
            &Al[row * 64 + (((kk * 4 + quad) ^ (row & 7)) * 8)]);
      }
#pragma unroll
      for (int ni = 0; ni < 4; ++ni) {
        int row = wn * 64 + ni * 16 + l16;
        bfr[ni] = *reinterpret_cast<const bf16x8*>(
            &Bl[row * 64 + (((kk * 4 + quad) ^ (row & 7)) * 8)]);
      }
#pragma unroll
      for (int mi = 0; mi < 4; ++mi)
#pragma unroll
        for (int ni = 0; ni < 4; ++ni)
          acc[mi][ni] = __builtin_amdgcn_mfma_f32_16x16x32_bf16(af[mi], bfr[ni], acc[mi][ni], 0, 0, 0);
    }
  }

#pragma unroll
  for (int mi = 0; mi < 4; ++mi)
#pragma unroll
    for (int ni = 0; ni < 4; ++ni)
#pragma unroll
      for (int r = 0; r < 4; ++r) {
        int row = m0 + wm * 64 + mi * 16 + quad * 4 + r;
        int col = n0 + wn * 64 + ni * 16 + l16;
        Cv[(size_t)row * N + col] = acc[mi][ni][r];
      }
}

// ---------------------------- flash attention ------------------------------
// Round-10 exact version (verified best). 32x32x16 MFMA, 4 waves x 32q,
// swapped QK^T, in-register P via cvt_pk + permlane32_swap, scalar psum,
// 2-deep LDS ring with per-tile vmcnt(0).
__global__ __launch_bounds__(256, 3) void attn(
    const us* __restrict__ QKV, const us* __restrict__ Vt,
    us* __restrict__ O) {
  __shared__ __align__(16) us Kb[2][64 * 64];
  __shared__ __align__(16) us Vb[2][64 * 64];
  __shared__ float Ls[4][32];
  const int bid = blockIdx.x;
  // balanced qt order: round-robin CU groups each get sum(2qt+2) == const
  const int j16 = bid >> 6;
  const int grp = j16 >> 2, pos = j16 & 3;
  const int qt = (grp == 0) ? 15 - pos : (grp == 1) ? pos
               : (grp == 2) ? 11 - pos : 4 + pos;
  const int bh = bid & 63;
  const int b = bh >> 4, h = bh & 15;
  const int q0 = qt * 128;
  const int tid = threadIdx.x, lane = tid & 63, w = tid >> 6;   // w in [0,4)
  const int l31 = lane & 31, hi = lane >> 5;
  const size_t rowbase = (size_t)b * 2048;
  const int qcol = h * 64;
  const int kcol = 1024 + h * 64;
  const int qw = q0 + w * 32;              // this wave's 32-row strip
  const int nT = 2 * qt + 2;

  // bank swizzle mask for reads (row = t*32 + l31; +32 doesn't change it)
  const int mr = (l31 & 7) ^ ((l31 >> 3) & 3);

  // Q B-fragments: lane(col=q=l31) holds Q[q][ds*16 + hi*8 + j]
  bf16x8 qf[4];
#pragma unroll
  for (int ds = 0; ds < 4; ++ds)
    qf[ds] = *reinterpret_cast<const bf16x8*>(
        &QKV[(rowbase + qw + l31) * 3072 + qcol + ds * 16 + hi * 8]);

  f32x16 oacc[2] = {};
  float psum = 0.f;

  const int rr8 = w * 8 + (lane >> 3);     // staged row within 32-row chunk
  const int ms = (rr8 & 7) ^ ((rr8 >> 3) & 3);
  const int uu = lane & 7;
  const int gu = uu ^ ms;                  // pre-swizzled source unit

  auto stage = [&](int kt, int buf) {
#pragma unroll
    for (int c = 0; c < 2; ++c) {
      int row = c * 32 + rr8;
      int base = __builtin_amdgcn_readfirstlane((c * 32 + w * 8) * 64);
      GL2LDS16(QKV + (rowbase + kt * 64 + row) * 3072 + kcol + gu * 8,
               &Kb[buf][base]);
      GL2LDS16(Vt + ((size_t)(bh * 64 + row)) * 2048 + kt * 64 + gu * 8,
               &Vb[buf][base]);
    }
  };

  stage(0, 0);

  for (int kt = 0; kt < nT; ++kt) {
    asm volatile("s_waitcnt vmcnt(0)" ::: "memory");  // own stage(kt) done
    asm volatile("s_barrier" ::: "memory");           // tile kt staged by all
    if (kt + 1 < nT) stage(kt + 1, (kt + 1) & 1);
    const us* Kl = &Kb[kt & 1][0];
    const us* Vl = &Vb[kt & 1][0];

    const int kdiff = qw + 31 - kt * 64;
    if (kdiff < 0) continue;                          // strip above diagonal
    const int tmax = (kdiff >= 32) ? 2 : 1;
    const bool do_mask = (kt * 64 + 63) > qw;

#pragma unroll
    for (int t = 0; t < 2; ++t) {
      if (t < tmax) {
        // swapped QK^T subtile: s = K_sub(t) * Q^T -> D[k][q], col=q=l31
        f32x16 s = {};
#pragma unroll
        for (int ds = 0; ds < 4; ++ds) {
          int row = t * 32 + l31;
          bf16x8 kf = *reinterpret_cast<const bf16x8*>(
              &Kl[row * 64 + (((ds * 2 + hi) ^ mr) * 8)]);
          s = __builtin_amdgcn_mfma_f32_32x32x16_bf16(kf, qf[ds], s, 0, 0, 0);
        }

        // exp2 + mask + per-lane row-sum
        float p[16];
        if (do_mask) {
#pragma unroll
          for (int r = 0; r < 16; ++r) {
            float e = __builtin_amdgcn_exp2f(s[r]);
            int kg = kt * 64 + t * 32 + (r & 3) + ((r >> 2) << 3) + hi * 4;
            p[r] = (kg <= qw + l31) ? e : 0.f;
            psum += p[r];
          }
        } else {
#pragma unroll
          for (int r = 0; r < 16; ++r) {
            p[r] = __builtin_amdgcn_exp2f(s[r]);
            psum += p[r];
          }
        }

        // pk[bb][w2] = bf16pair(p[4bb+2w2], p[4bb+2w2+1]); block (2bb+hi) of k
        u32 pk[4][2];
#pragma unroll
        for (int bb = 0; bb < 4; ++bb)
#pragma unroll
          for (int w2 = 0; w2 < 2; ++w2)
            asm("v_cvt_pk_bf16_f32 %0, %1, %2"
                : "=v"(pk[bb][w2])
                : "v"(p[4 * bb + 2 * w2]), "v"(p[4 * bb + 2 * w2 + 1]));

        // slice s2: dest half hi needs pk[2*s2+hi] from both halves
#pragma unroll
        for (int s2 = 0; s2 < 2; ++s2) {
          u32 pa[4];
#pragma unroll
          for (int w2 = 0; w2 < 2; ++w2) {
            u32 a = pk[2 * s2][w2];
            u32 c = pk[2 * s2 + 1][w2];
            asm volatile("v_permlane32_swap_b32 %0, %1" : "+v"(a), "+v"(c));
            pa[w2] = a;            // j 0..3  (k = 16*s2 + 8*hi + 0..3)
            pa[2 + w2] = c;        // j 4..7
          }
          union { u32 u[4]; bf16x8 v; } pu;
          pu.u[0] = pa[0]; pu.u[1] = pa[1]; pu.u[2] = pa[2]; pu.u[3] = pa[3];
          bf16x8 paf = pu.v;
          int ks = t * 2 + s2;     // 16k slice within the 64k tile
#pragma unroll
          for (int dt = 0; dt < 2; ++dt) {
            int row = dt * 32 + l31;
            bf16x8 vf = *reinterpret_cast<const bf16x8*>(
                &Vl[row * 64 + (((ks * 2 + hi) ^ mr) * 8)]);
            oacc[dt] = __builtin_amdgcn_mfma_f32_32x32x16_bf16(paf, vf, oacc[dt], 0, 0, 0);
          }
        }
      }
    }
  }

  // combine psum halves (disjoint k-sets) and broadcast 1/sum via LDS
  {
    float a = psum, c = psum;
    asm volatile("v_permlane32_swap_b32 %0, %1" : "+v"(a), "+v"(c));
    float invl = 1.0f / (a + c);
    if (!hi) Ls[w][l31] = invl;
    asm volatile("s_waitcnt lgkmcnt(0)" ::: "memory");  // wave-local
  }
  float inv[16];
#pragma unroll
  for (int r = 0; r < 16; ++r)
    inv[r] = Ls[w][(r & 3) + ((r >> 2) << 3) + hi * 4];
#pragma unroll
  for (int dt = 0; dt < 2; ++dt)
#pragma unroll
    for (int r = 0; r < 16; ++r) {
      int qg = qw + (r & 3) + ((r >> 2) << 3) + hi * 4;
      O[(rowbase + qg) * 1024 + qcol + dt * 32 + l31] = f2bf(oacc[dt][r] * inv[r]);
    }
}

// ------------------------------- launcher ----------------------------------
extern "C" void kernel_launch(void* const* d_in, const int* in_sizes, int n_in,
                              void* d_out, int out_size, void* d_ws, size_t ws_size,
                              hipStream_t stream) {
  const float* x = (const float*)d_in[0];
  const float* wq = (const float*)d_in[1];
  const float* wk = (const float*)d_in[2];
  const float* wv = (const float*)d_in[3];
  const float* wo = (const float*)d_in[4];

  const int BT = 8192, E = 1024;
  const size_t NX = (size_t)BT * E;
  const size_t NW = (size_t)E * E;

  us* xb = (us*)d_ws;                 // [8192][1024]; later reused as O
  us* wbuf = xb + NX;                 // wq|wk|wv|wo bf16
  us* QKV = wbuf + 4 * NW;            // [8192][3072] (V cols unused)
  us* VtB = QKV + (size_t)BT * 3 * E; // [64 bh][64 d][2048], natural k-order
  us* Ob = xb;

  cast_all<<<(int)((NX + 4 * NW) / 8 / 256), 256, 0, stream>>>(x, wq, wk, wv, wo, xb, wbuf);

  gemm_qkv<<<1536, 256, 0, stream>>>(xb, wbuf, QKV, VtB);
  attn<<<1024, 256, 0, stream>>>(QKV, VtB, Ob);
  gemm_out<<<dim3(8, 64), 256, 0, stream>>>(Ob, wbuf + 3 * NW, (float*)d_out, BT, E, E);
}